// Round 10
// baseline (615.323 us; speedup 1.0000x reference)
//
#include <hip/hip_runtime.h>
#include <hip/hip_cooperative_groups.h>
#include <cstdint>
#include <cstddef>

#define NN 100000
#define NE 1600000
#define DIM 256

// workspace layout (ints)
#define NA 100352            // NN rounded up, 4B ints
#define CSR_IOFF (4*NA + 512)
// byte offsets for bf16 regions
#define HS_OFF   8007680ull                     // (CSR_IOFF + NE) * 4
#define WT_OFF   (HS_OFF + (size_t)NN*DIM*2)    // weight packed, 128 KB
#define WS_NEED  (WT_OFF + (size_t)DIM*DIM*2)

namespace cg = cooperative_groups;

typedef short bf16x8 __attribute__((ext_vector_type(8)));
typedef float f32x4 __attribute__((ext_vector_type(4)));
typedef unsigned short u16x4 __attribute__((ext_vector_type(4)));

__device__ __forceinline__ float bf2f(unsigned short u) {
    return __uint_as_float(((unsigned)u) << 16);
}
__device__ __forceinline__ unsigned short f2bf(float f) {
    unsigned u = __float_as_uint(f);
    u += 0x7FFF + ((u >> 16) & 1);   // round-to-nearest-even
    return (unsigned short)(u >> 16);
}

// ---- ONE cooperative kernel for ALL preprocessing --------------------------
// 256 blocks x 1024 threads (1 block/CU, 16 waves/CU, co-resident).
// P0 zero degs | P1 histograms | P2 two-level scan -> rowp,cnt | P3 fill+hscale+wtpack
__global__ __launch_bounds__(1024) void k_prep(
        const int* __restrict__ src, const int* __restrict__ dst,
        const float* __restrict__ h, const float* __restrict__ W,
        int* __restrict__ outd, int* __restrict__ ind,
        int* __restrict__ rowp, int* __restrict__ cnt,
        int* __restrict__ bsum, int* __restrict__ csr,
        unsigned short* __restrict__ hs, unsigned short* __restrict__ wtp) {
    cg::grid_group grid = cg::this_grid();
    __shared__ int tmp[1024];
    const int lt = threadIdx.x;
    const int gid = blockIdx.x * 1024 + lt;
    const int gstride = gridDim.x * 1024;    // 262144

    // ---- P0: zero outd+ind (contiguous 2*NA ints) ----
    for (int i = gid; i < 2 * NA; i += gstride) outd[i] = 0;
    grid.sync();

    // ---- P1: degree histograms ----
    for (int e = gid; e < NE; e += gstride) {
        atomicAdd(&outd[src[e]], 1);
        atomicAdd(&ind[dst[e]], 1);
    }
    grid.sync();

    // ---- P2a: block-local inclusive scan of ind (1024/block) ----
    int x = (gid < NN) ? ind[gid] : 0;
    tmp[lt] = x;
    __syncthreads();
    for (int off = 1; off < 1024; off <<= 1) {
        int v = (lt >= off) ? tmp[lt - off] : 0;
        __syncthreads();
        tmp[lt] += v;
        __syncthreads();
    }
    int excl_local = tmp[lt] - x;
    if (lt == 1023) bsum[blockIdx.x] = tmp[lt];
    grid.sync();

    // ---- P2b: block 0 scans the 256 block sums (padded scan) ----
    if (blockIdx.x == 0) {
        int bv = (lt < 256) ? bsum[lt] : 0;
        tmp[lt] = bv;
        __syncthreads();
        for (int off = 1; off < 1024; off <<= 1) {
            int v = (lt >= off) ? tmp[lt - off] : 0;
            __syncthreads();
            tmp[lt] += v;
            __syncthreads();
        }
        if (lt < 256) bsum[lt] = tmp[lt] - bv;   // exclusive block offsets
    }
    grid.sync();

    // ---- P2c: finalize rowp + cnt (fill cursor seeded with rowp) ----
    if (gid < NN) {
        int v = excl_local + bsum[blockIdx.x];
        rowp[gid] = v;
        cnt[gid] = v;
    }
    if (gid == NN) rowp[NN] = NE;
    grid.sync();

    // ---- P3: independent passes, overlapped in one phase ----
    // weight -> bf16 MFMA-fragment-packed (tiny)
    for (int p = gid; p < DIM * DIM; p += gstride) {
        int j = p & 7, l = (p >> 3) & 63, t = (p >> 9) & 15, ks = p >> 13;
        wtp[p] = f2bf(W[(ks * 32 + (l >> 4) * 8 + j) * DIM + t * 16 + (l & 15)]);
    }
    // CSR fill (atomic cursor scatter)
    for (int e = gid; e < NE; e += gstride) {
        int p = atomicAdd(&cnt[dst[e]], 1);
        csr[p] = src[e];
    }
    // h_scaled = bf16(h * rsqrt(max(out_deg,1))) — streaming 153 MB
    for (int i = gid; i < NN * (DIM / 4); i += gstride) {
        int node = i >> 6;
        float s = rsqrtf(fmaxf((float)outd[node], 1.0f));
        float4 v = ((const float4*)h)[i];
        u16x4 o;
        o.x = f2bf(v.x * s);
        o.y = f2bf(v.y * s);
        o.z = f2bf(v.z * s);
        o.w = f2bf(v.w * s);
        ((u16x4*)hs)[i] = o;
    }
}

// ---- FUSED aggregate + GEMM + bias + ELU (unchanged from R9) ---------------
__global__ __launch_bounds__(256) void k_aggemm(const unsigned short* __restrict__ hs,
                                                const int* __restrict__ csr,
                                                const int* __restrict__ rowp,
                                                const int* __restrict__ ind,
                                                const unsigned short* __restrict__ wtp,
                                                const float* __restrict__ bias,
                                                float* __restrict__ out) {
    __shared__ short As[16][264];
    int wave = threadIdx.x >> 6;
    int lane = threadIdx.x & 63;
    int nb = blockIdx.x * 16;

    // ---- phase 1: aggregate 4 nodes per wave ----
    for (int i = 0; i < 4; ++i) {
        int r = wave * 4 + i;
        int node = nb + r;
        int e0 = rowp[node], e1 = rowp[node + 1];
        float a0 = 0.f, a1 = 0.f, a2 = 0.f, a3 = 0.f;
        int e = e0;
        for (; e + 3 < e1; e += 4) {
            int s0 = __builtin_nontemporal_load(csr + e);
            int s1 = __builtin_nontemporal_load(csr + e + 1);
            int s2 = __builtin_nontemporal_load(csr + e + 2);
            int s3 = __builtin_nontemporal_load(csr + e + 3);
            u16x4 u0 = ((const u16x4*)(hs + (size_t)s0 * DIM))[lane];
            u16x4 u1 = ((const u16x4*)(hs + (size_t)s1 * DIM))[lane];
            u16x4 u2 = ((const u16x4*)(hs + (size_t)s2 * DIM))[lane];
            u16x4 u3 = ((const u16x4*)(hs + (size_t)s3 * DIM))[lane];
            a0 += (bf2f(u0.x) + bf2f(u1.x)) + (bf2f(u2.x) + bf2f(u3.x));
            a1 += (bf2f(u0.y) + bf2f(u1.y)) + (bf2f(u2.y) + bf2f(u3.y));
            a2 += (bf2f(u0.z) + bf2f(u1.z)) + (bf2f(u2.z) + bf2f(u3.z));
            a3 += (bf2f(u0.w) + bf2f(u1.w)) + (bf2f(u2.w) + bf2f(u3.w));
        }
        for (; e < e1; ++e) {
            int s0 = __builtin_nontemporal_load(csr + e);
            u16x4 u = ((const u16x4*)(hs + (size_t)s0 * DIM))[lane];
            a0 += bf2f(u.x);
            a1 += bf2f(u.y);
            a2 += bf2f(u.z);
            a3 += bf2f(u.w);
        }
        float nd = rsqrtf(fmaxf((float)ind[node], 1.0f));
        u16x4 o;
        o.x = f2bf(a0 * nd);
        o.y = f2bf(a1 * nd);
        o.z = f2bf(a2 * nd);
        o.w = f2bf(a3 * nd);
        *(u16x4*)&As[r][4 * lane] = o;   // linear across lanes: conflict-free
    }
    __syncthreads();

    // ---- phase 2: 16x256 GEMM quadrant per wave ----
    const short* B = (const short*)wtp + lane * 8;
    f32x4 acc[4];
#pragma unroll
    for (int tt = 0; tt < 4; ++tt) acc[tt] = (f32x4){0.f, 0.f, 0.f, 0.f};

    int fr = lane & 15;      // A-row / C-col fragment index
    int q  = lane >> 4;      // k-group / C-row group
    for (int ks = 0; ks < 8; ++ks) {
        bf16x8 a = *(const bf16x8*)&As[fr][ks * 32 + q * 8];
#pragma unroll
        for (int tt = 0; tt < 4; ++tt) {
            int t = wave * 4 + tt;
            bf16x8 b = *(const bf16x8*)(B + (size_t)(ks * 16 + t) * 512);
            acc[tt] = __builtin_amdgcn_mfma_f32_16x16x32_bf16(a, b, acc[tt], 0, 0, 0);
        }
    }

    // ---- epilogue: bias + ELU + store ----
    int rbase = nb + q * 4;
#pragma unroll
    for (int tt = 0; tt < 4; ++tt) {
        int col = wave * 64 + tt * 16 + fr;
        float bv = bias[col];
#pragma unroll
        for (int i = 0; i < 4; ++i) {
            float v = acc[tt][i] + bv;
            v = v > 0.f ? v : expm1f(v);
            __builtin_nontemporal_store(v, &out[(size_t)(rbase + i) * DIM + col]);
        }
    }
}

extern "C" void kernel_launch(void* const* d_in, const int* in_sizes, int n_in,
                              void* d_out, int out_size, void* d_ws, size_t ws_size,
                              hipStream_t stream) {
    const int*   src  = (const int*)d_in[3];
    const int*   dst  = (const int*)d_in[4];
    const float* h    = (const float*)d_in[0];
    const float* W    = (const float*)d_in[1];
    const float* bias = (const float*)d_in[2];
    float* out = (float*)d_out;

    if (ws_size < WS_NEED) return;  // insufficient scratch -> loud failure

    char* w = (char*)d_ws;
    int* outd = (int*)w;
    int* ind  = outd + NA;
    int* rowp = outd + 2 * NA;
    int* cnt  = outd + 3 * NA;
    int* bsum = outd + 4 * NA;           // 256 ints, within the 512-int gap
    int* csr  = outd + CSR_IOFF;
    unsigned short* hs  = (unsigned short*)(w + HS_OFF);
    unsigned short* wtp = (unsigned short*)(w + WT_OFF);

    void* args[] = {(void*)&src, (void*)&dst, (void*)&h, (void*)&W,
                    (void*)&outd, (void*)&ind, (void*)&rowp, (void*)&cnt,
                    (void*)&bsum, (void*)&csr, (void*)&hs, (void*)&wtp};
    hipLaunchCooperativeKernel(reinterpret_cast<void*>(k_prep),
                               dim3(256), dim3(1024), args, 0, stream);

    k_aggemm<<<NN / 16, 256, 0, stream>>>(hs, csr, rowp, ind, wtp, bias, out);
}

// Round 11
// 385.665 us; speedup vs baseline: 1.5955x; 1.5955x over previous
//
#include <hip/hip_runtime.h>
#include <cstdint>
#include <cstddef>

#define NN 100000
#define NE 1600000
#define DIM 256

// workspace layout (ints)
#define NA 100352            // NN rounded up, 4B ints
#define CSR_IOFF (4*NA + 512)
// byte offsets
#define HS_OFF   8007680ull                     // (CSR_IOFF + NE) * 4
#define WT_OFF   (HS_OFF + (size_t)NN*DIM*2)    // weight packed, 128 KB
#define RANK_OFF (WT_OFF + (size_t)DIM*DIM*2)   // rank[NE], 6.4 MB
#define WS_NEED  (RANK_OFF + (size_t)NE*4)

typedef short bf16x8 __attribute__((ext_vector_type(8)));
typedef float f32x4 __attribute__((ext_vector_type(4)));
typedef unsigned short u16x4 __attribute__((ext_vector_type(4)));

__device__ __forceinline__ float bf2f(unsigned short u) {
    return __uint_as_float(((unsigned)u) << 16);
}
__device__ __forceinline__ unsigned short f2bf(float f) {
    unsigned u = __float_as_uint(f);
    u += 0x7FFF + ((u >> 16) & 1);   // round-to-nearest-even
    return (unsigned short)(u >> 16);
}

// ---- degree histograms + slot ranks (ONE atomic pass) ----------------------
// rank[e] = #earlier edges with same dst  ==> ind ends as in_deg histogram.
__global__ void k_count(const int* __restrict__ src, const int* __restrict__ dst,
                        int* __restrict__ outd, int* __restrict__ ind,
                        int* __restrict__ rank) {
    int e = blockIdx.x * blockDim.x + threadIdx.x;
    if (e < NE) {
        atomicAdd(&outd[src[e]], 1);
        rank[e] = atomicAdd(&ind[dst[e]], 1);
    }
}

// ---- 3-kernel exclusive prefix scan of in_deg -> row_ptr -------------------
#define SCAN_NB 98   // ceil(NN/1024)

__global__ void k_scan1(const int* __restrict__ ind, int* __restrict__ rowp,
                        int* __restrict__ bsum) {
    __shared__ int tmp[1024];
    int t = threadIdx.x;
    int i = blockIdx.x * 1024 + t;
    int x = (i < NN) ? ind[i] : 0;
    tmp[t] = x;
    __syncthreads();
    for (int off = 1; off < 1024; off <<= 1) {
        int v = (t >= off) ? tmp[t - off] : 0;
        __syncthreads();
        tmp[t] += v;
        __syncthreads();
    }
    if (i < NN) rowp[i] = tmp[t] - x;           // exclusive within block
    if (t == 1023) bsum[blockIdx.x] = tmp[t];   // block total
}

__global__ void k_scan2(int* __restrict__ bsum) {
    __shared__ int tmp[128];
    int t = threadIdx.x;
    int x = (t < SCAN_NB) ? bsum[t] : 0;
    tmp[t] = x;
    __syncthreads();
    for (int off = 1; off < 128; off <<= 1) {
        int v = (t >= off) ? tmp[t - off] : 0;
        __syncthreads();
        tmp[t] += v;
        __syncthreads();
    }
    if (t < SCAN_NB) bsum[t] = tmp[t] - x;      // exclusive
}

__global__ void k_scan3(int* __restrict__ rowp, const int* __restrict__ bsum) {
    int i = blockIdx.x * 1024 + threadIdx.x;
    if (i < NN) rowp[i] += bsum[blockIdx.x];
    if (i == 0) rowp[NN] = NE;
}

// ---- fused streaming finish: CSR scatter (no atomics) + hscale + wt pack ---
__global__ __launch_bounds__(256) void k_finish(
        const int* __restrict__ src, const int* __restrict__ dst,
        const int* __restrict__ rank, const int* __restrict__ rowp,
        const int* __restrict__ outd, const float* __restrict__ h,
        const float* __restrict__ W,
        int* __restrict__ csr, unsigned short* __restrict__ hs,
        unsigned short* __restrict__ wtp) {
    int gid = blockIdx.x * blockDim.x + threadIdx.x;
    int gstride = gridDim.x * blockDim.x;

    // weight -> bf16 MFMA-fragment-packed (tiny, 64K elems)
    for (int p = gid; p < DIM * DIM; p += gstride) {
        int j = p & 7, l = (p >> 3) & 63, t = (p >> 9) & 15, ks = p >> 13;
        wtp[p] = f2bf(W[(ks * 32 + (l >> 4) * 8 + j) * DIM + t * 16 + (l & 15)]);
    }
    // CSR scatter: slot precomputed by k_count -> zero atomics
    for (int e = gid; e < NE; e += gstride) {
        csr[rowp[dst[e]] + rank[e]] = src[e];
    }
    // h_scaled = bf16(h * rsqrt(max(out_deg,1))), 153 MB stream
    for (int i = gid; i < NN * (DIM / 4); i += gstride) {
        int node = i >> 6;
        float s = rsqrtf(fmaxf((float)outd[node], 1.0f));
        float4 v = ((const float4*)h)[i];
        u16x4 o;
        o.x = f2bf(v.x * s);
        o.y = f2bf(v.y * s);
        o.z = f2bf(v.z * s);
        o.w = f2bf(v.w * s);
        ((u16x4*)hs)[i] = o;
    }
}

// ---- FUSED aggregate + GEMM + bias + ELU (unchanged, R9-passing) -----------
__global__ __launch_bounds__(256) void k_aggemm(const unsigned short* __restrict__ hs,
                                                const int* __restrict__ csr,
                                                const int* __restrict__ rowp,
                                                const int* __restrict__ ind,
                                                const unsigned short* __restrict__ wtp,
                                                const float* __restrict__ bias,
                                                float* __restrict__ out) {
    __shared__ short As[16][264];
    int wave = threadIdx.x >> 6;
    int lane = threadIdx.x & 63;
    int nb = blockIdx.x * 16;

    // ---- phase 1: aggregate 4 nodes per wave ----
    for (int i = 0; i < 4; ++i) {
        int r = wave * 4 + i;
        int node = nb + r;
        int e0 = rowp[node], e1 = rowp[node + 1];
        float a0 = 0.f, a1 = 0.f, a2 = 0.f, a3 = 0.f;
        int e = e0;
        for (; e + 3 < e1; e += 4) {
            int s0 = __builtin_nontemporal_load(csr + e);
            int s1 = __builtin_nontemporal_load(csr + e + 1);
            int s2 = __builtin_nontemporal_load(csr + e + 2);
            int s3 = __builtin_nontemporal_load(csr + e + 3);
            u16x4 u0 = ((const u16x4*)(hs + (size_t)s0 * DIM))[lane];
            u16x4 u1 = ((const u16x4*)(hs + (size_t)s1 * DIM))[lane];
            u16x4 u2 = ((const u16x4*)(hs + (size_t)s2 * DIM))[lane];
            u16x4 u3 = ((const u16x4*)(hs + (size_t)s3 * DIM))[lane];
            a0 += (bf2f(u0.x) + bf2f(u1.x)) + (bf2f(u2.x) + bf2f(u3.x));
            a1 += (bf2f(u0.y) + bf2f(u1.y)) + (bf2f(u2.y) + bf2f(u3.y));
            a2 += (bf2f(u0.z) + bf2f(u1.z)) + (bf2f(u2.z) + bf2f(u3.z));
            a3 += (bf2f(u0.w) + bf2f(u1.w)) + (bf2f(u2.w) + bf2f(u3.w));
        }
        for (; e < e1; ++e) {
            int s0 = __builtin_nontemporal_load(csr + e);
            u16x4 u = ((const u16x4*)(hs + (size_t)s0 * DIM))[lane];
            a0 += bf2f(u.x);
            a1 += bf2f(u.y);
            a2 += bf2f(u.z);
            a3 += bf2f(u.w);
        }
        float nd = rsqrtf(fmaxf((float)ind[node], 1.0f));
        u16x4 o;
        o.x = f2bf(a0 * nd);
        o.y = f2bf(a1 * nd);
        o.z = f2bf(a2 * nd);
        o.w = f2bf(a3 * nd);
        *(u16x4*)&As[r][4 * lane] = o;   // linear across lanes: conflict-free
    }
    __syncthreads();

    // ---- phase 2: 16x256 GEMM quadrant per wave ----
    const short* B = (const short*)wtp + lane * 8;
    f32x4 acc[4];
#pragma unroll
    for (int tt = 0; tt < 4; ++tt) acc[tt] = (f32x4){0.f, 0.f, 0.f, 0.f};

    int fr = lane & 15;      // A-row / C-col fragment index
    int q  = lane >> 4;      // k-group / C-row group
    for (int ks = 0; ks < 8; ++ks) {
        bf16x8 a = *(const bf16x8*)&As[fr][ks * 32 + q * 8];
#pragma unroll
        for (int tt = 0; tt < 4; ++tt) {
            int t = wave * 4 + tt;
            bf16x8 b = *(const bf16x8*)(B + (size_t)(ks * 16 + t) * 512);
            acc[tt] = __builtin_amdgcn_mfma_f32_16x16x32_bf16(a, b, acc[tt], 0, 0, 0);
        }
    }

    // ---- epilogue: bias + ELU + store ----
    int rbase = nb + q * 4;
#pragma unroll
    for (int tt = 0; tt < 4; ++tt) {
        int col = wave * 64 + tt * 16 + fr;
        float bv = bias[col];
#pragma unroll
        for (int i = 0; i < 4; ++i) {
            float v = acc[tt][i] + bv;
            v = v > 0.f ? v : expm1f(v);
            __builtin_nontemporal_store(v, &out[(size_t)(rbase + i) * DIM + col]);
        }
    }
}

extern "C" void kernel_launch(void* const* d_in, const int* in_sizes, int n_in,
                              void* d_out, int out_size, void* d_ws, size_t ws_size,
                              hipStream_t stream) {
    const float* h    = (const float*)d_in[0];
    const float* W    = (const float*)d_in[1];
    const float* bias = (const float*)d_in[2];
    const int*   src  = (const int*)d_in[3];
    const int*   dst  = (const int*)d_in[4];
    float* out = (float*)d_out;

    if (ws_size < WS_NEED) return;  // insufficient scratch -> loud failure

    char* w = (char*)d_ws;
    int* outd = (int*)w;
    int* ind  = outd + NA;
    int* rowp = outd + 2 * NA;
    int* bsum = outd + 4 * NA;           // 256 ints, within the 512-int gap
    int* csr  = outd + CSR_IOFF;
    unsigned short* hs  = (unsigned short*)(w + HS_OFF);
    unsigned short* wtp = (unsigned short*)(w + WT_OFF);
    int* rank = (int*)(w + RANK_OFF);

    hipMemsetAsync(outd, 0, (size_t)2 * NA * sizeof(int), stream);  // outd+ind

    k_count<<<NE / 256, 256, 0, stream>>>(src, dst, outd, ind, rank);
    k_scan1<<<SCAN_NB, 1024, 0, stream>>>(ind, rowp, bsum);
    k_scan2<<<1, 128, 0, stream>>>(bsum);
    k_scan3<<<SCAN_NB, 1024, 0, stream>>>(rowp, bsum);
    k_finish<<<2048, 256, 0, stream>>>(src, dst, rank, rowp, outd, h, W,
                                       csr, hs, wtp);
    k_aggemm<<<NN / 16, 256, 0, stream>>>(hs, csr, rowp, ind, wtp, bias, out);
}

// Round 13
// 337.538 us; speedup vs baseline: 1.8230x; 1.1426x over previous
//
#include <hip/hip_runtime.h>
#include <cstdint>
#include <cstddef>

#define NN 100000
#define NE 1600000
#define DIM 256

// workspace layout (ints)
#define NA 100352            // NN rounded up, 4B ints
#define CSR_IOFF (4*NA + 512)
// byte offsets
#define HS_OFF   8007680ull                     // (CSR_IOFF + NE) * 4
#define WT_OFF   (HS_OFF + (size_t)NN*DIM*2)    // weight packed, 128 KB
#define RANK_OFF (WT_OFF + (size_t)DIM*DIM*2)   // rank[NE], 6.4 MB
#define WS_NEED  (RANK_OFF + (size_t)NE*4)

typedef short bf16x8 __attribute__((ext_vector_type(8)));
typedef float f32x4 __attribute__((ext_vector_type(4)));
typedef unsigned short u16x4 __attribute__((ext_vector_type(4)));

__device__ __forceinline__ float bf2f(unsigned short u) {
    return __uint_as_float(((unsigned)u) << 16);
}
__device__ __forceinline__ unsigned short f2bf(float f) {
    unsigned u = __float_as_uint(f);
    u += 0x7FFF + ((u >> 16) & 1);   // round-to-nearest-even
    return (unsigned short)(u >> 16);
}

// ---- fused: degree histograms + slot ranks + h->bf16 convert ---------------
// Atomic pass is latency-bound with ~zero BW/VALU use; the 153 MB convert
// stream overlaps it inside one kernel. hs is RAW bf16(h) (norm_src applied
// later at gather time), so the convert has no dependency on the histogram.
__global__ __launch_bounds__(256) void k_count_conv(
        const int* __restrict__ src, const int* __restrict__ dst,
        const float* __restrict__ h,
        int* __restrict__ outd, int* __restrict__ ind,
        int* __restrict__ rank, unsigned short* __restrict__ hs) {
    int gid = blockIdx.x * blockDim.x + threadIdx.x;
    int gstride = gridDim.x * blockDim.x;
    for (int e = gid; e < NE; e += gstride) {
        atomicAdd(&outd[src[e]], 1);
        rank[e] = atomicAdd(&ind[dst[e]], 1);
    }
    for (int i = gid; i < NN * (DIM / 4); i += gstride) {
        float4 v = ((const float4*)h)[i];
        u16x4 o;
        o.x = f2bf(v.x);
        o.y = f2bf(v.y);
        o.z = f2bf(v.z);
        o.w = f2bf(v.w);
        ((u16x4*)hs)[i] = o;
    }
}

// ---- 3-kernel exclusive prefix scan of in_deg -> row_ptr -------------------
#define SCAN_NB 98   // ceil(NN/1024)

__global__ void k_scan1(const int* __restrict__ ind, int* __restrict__ rowp,
                        int* __restrict__ bsum) {
    __shared__ int tmp[1024];
    int t = threadIdx.x;
    int i = blockIdx.x * 1024 + t;
    int x = (i < NN) ? ind[i] : 0;
    tmp[t] = x;
    __syncthreads();
    for (int off = 1; off < 1024; off <<= 1) {
        int v = (t >= off) ? tmp[t - off] : 0;
        __syncthreads();
        tmp[t] += v;
        __syncthreads();
    }
    if (i < NN) rowp[i] = tmp[t] - x;           // exclusive within block
    if (t == 1023) bsum[blockIdx.x] = tmp[t];   // block total
}

__global__ void k_scan2(int* __restrict__ bsum) {
    __shared__ int tmp[128];
    int t = threadIdx.x;
    int x = (t < SCAN_NB) ? bsum[t] : 0;
    tmp[t] = x;
    __syncthreads();
    for (int off = 1; off < 128; off <<= 1) {
        int v = (t >= off) ? tmp[t - off] : 0;
        __syncthreads();
        tmp[t] += v;
        __syncthreads();
    }
    if (t < SCAN_NB) bsum[t] = tmp[t] - x;      // exclusive
}

// finalize rowp; also emit normsrc[i] = rsqrt(max(out_deg,1)) as f32 table
__global__ void k_scan3(int* __restrict__ rowp, const int* __restrict__ bsum,
                        const int* __restrict__ outd, float* __restrict__ normsrc) {
    int i = blockIdx.x * 1024 + threadIdx.x;
    if (i < NN) {
        rowp[i] += bsum[blockIdx.x];
        normsrc[i] = rsqrtf(fmaxf((float)outd[i], 1.0f));
    }
    if (i == 0) rowp[NN] = NE;
}

// ---- streaming finish: CSR scatter (no atomics) + weight pack --------------
__global__ __launch_bounds__(256) void k_scatter(
        const int* __restrict__ src, const int* __restrict__ dst,
        const int* __restrict__ rank, const int* __restrict__ rowp,
        const float* __restrict__ W,
        int* __restrict__ csr, unsigned short* __restrict__ wtp) {
    int gid = blockIdx.x * blockDim.x + threadIdx.x;
    int gstride = gridDim.x * blockDim.x;
    // weight -> bf16 MFMA-fragment-packed (tiny, 64K elems)
    for (int p = gid; p < DIM * DIM; p += gstride) {
        int j = p & 7, l = (p >> 3) & 63, t = (p >> 9) & 15, ks = p >> 13;
        wtp[p] = f2bf(W[(ks * 32 + (l >> 4) * 8 + j) * DIM + t * 16 + (l & 15)]);
    }
    // CSR scatter: slot precomputed by k_count_conv -> zero atomics
    for (int e = gid; e < NE; e += gstride) {
        csr[rowp[dst[e]] + rank[e]] = src[e];
    }
}

// ---- FUSED aggregate + GEMM + bias + ELU -----------------------------------
// Phase 1 per wave: 4 nodes; row's csr entries loaded ONCE (coalesced, one
// 4B/lane load per 64 edges), indices broadcast via readlane -> gathers have
// SGPR bases, csr latency leaves the dependency chain. norm_src applied per
// edge via fma with L2-resident f32 table.
__global__ __launch_bounds__(256) void k_aggemm(const unsigned short* __restrict__ hs,
                                                const int* __restrict__ csr,
                                                const int* __restrict__ rowp,
                                                const int* __restrict__ ind,
                                                const float* __restrict__ normsrc,
                                                const unsigned short* __restrict__ wtp,
                                                const float* __restrict__ bias,
                                                float* __restrict__ out) {
    __shared__ short As[16][264];
    int wave = threadIdx.x >> 6;
    int lane = threadIdx.x & 63;
    int nb = blockIdx.x * 16;

    // ---- phase 1: aggregate 4 nodes per wave ----
    for (int i = 0; i < 4; ++i) {
        int r = wave * 4 + i;
        int node = nb + r;
        int e0 = rowp[node], e1 = rowp[node + 1];
        float a0 = 0.f, a1 = 0.f, a2 = 0.f, a3 = 0.f;
        for (int base = e0; base < e1; base += 64) {
            int n = e1 - base;
            if (n > 64) n = 64;
            int idx = base + lane;
            int csrv = (idx < e1) ? csr[idx] : 0;
            int j = 0;
            for (; j + 3 < n; j += 4) {
                int s0 = __builtin_amdgcn_readlane(csrv, j);
                int s1 = __builtin_amdgcn_readlane(csrv, j + 1);
                int s2 = __builtin_amdgcn_readlane(csrv, j + 2);
                int s3 = __builtin_amdgcn_readlane(csrv, j + 3);
                float n0 = normsrc[s0], n1 = normsrc[s1];
                float n2 = normsrc[s2], n3 = normsrc[s3];
                u16x4 u0 = ((const u16x4*)(hs + (size_t)s0 * DIM))[lane];
                u16x4 u1 = ((const u16x4*)(hs + (size_t)s1 * DIM))[lane];
                u16x4 u2 = ((const u16x4*)(hs + (size_t)s2 * DIM))[lane];
                u16x4 u3 = ((const u16x4*)(hs + (size_t)s3 * DIM))[lane];
                a0 = fmaf(bf2f(u0.x), n0, fmaf(bf2f(u1.x), n1,
                     fmaf(bf2f(u2.x), n2, fmaf(bf2f(u3.x), n3, a0))));
                a1 = fmaf(bf2f(u0.y), n0, fmaf(bf2f(u1.y), n1,
                     fmaf(bf2f(u2.y), n2, fmaf(bf2f(u3.y), n3, a1))));
                a2 = fmaf(bf2f(u0.z), n0, fmaf(bf2f(u1.z), n1,
                     fmaf(bf2f(u2.z), n2, fmaf(bf2f(u3.z), n3, a2))));
                a3 = fmaf(bf2f(u0.w), n0, fmaf(bf2f(u1.w), n1,
                     fmaf(bf2f(u2.w), n2, fmaf(bf2f(u3.w), n3, a3))));
            }
            for (; j < n; ++j) {
                int s0 = __builtin_amdgcn_readlane(csrv, j);
                float n0 = normsrc[s0];
                u16x4 u = ((const u16x4*)(hs + (size_t)s0 * DIM))[lane];
                a0 = fmaf(bf2f(u.x), n0, a0);
                a1 = fmaf(bf2f(u.y), n0, a1);
                a2 = fmaf(bf2f(u.z), n0, a2);
                a3 = fmaf(bf2f(u.w), n0, a3);
            }
        }
        float nd = rsqrtf(fmaxf((float)ind[node], 1.0f));
        u16x4 o;
        o.x = f2bf(a0 * nd);
        o.y = f2bf(a1 * nd);
        o.z = f2bf(a2 * nd);
        o.w = f2bf(a3 * nd);
        *(u16x4*)&As[r][4 * lane] = o;   // linear across lanes: conflict-free
    }
    __syncthreads();

    // ---- phase 2: 16x256 GEMM quadrant per wave ----
    const short* B = (const short*)wtp + lane * 8;
    f32x4 acc[4];
#pragma unroll
    for (int tt = 0; tt < 4; ++tt) acc[tt] = (f32x4){0.f, 0.f, 0.f, 0.f};

    int fr = lane & 15;      // A-row / C-col fragment index
    int q  = lane >> 4;      // k-group / C-row group
    for (int ks = 0; ks < 8; ++ks) {
        bf16x8 a = *(const bf16x8*)&As[fr][ks * 32 + q * 8];
#pragma unroll
        for (int tt = 0; tt < 4; ++tt) {
            int t = wave * 4 + tt;
            bf16x8 b = *(const bf16x8*)(B + (size_t)(ks * 16 + t) * 512);
            acc[tt] = __builtin_amdgcn_mfma_f32_16x16x32_bf16(a, b, acc[tt], 0, 0, 0);
        }
    }

    // ---- epilogue: bias + ELU + store ----
    int rbase = nb + q * 4;
#pragma unroll
    for (int tt = 0; tt < 4; ++tt) {
        int col = wave * 64 + tt * 16 + fr;
        float bv = bias[col];
#pragma unroll
        for (int i = 0; i < 4; ++i) {
            float v = acc[tt][i] + bv;
            v = v > 0.f ? v : expm1f(v);
            __builtin_nontemporal_store(v, &out[(size_t)(rbase + i) * DIM + col]);
        }
    }
}

extern "C" void kernel_launch(void* const* d_in, const int* in_sizes, int n_in,
                              void* d_out, int out_size, void* d_ws, size_t ws_size,
                              hipStream_t stream) {
    const float* h    = (const float*)d_in[0];
    const float* W    = (const float*)d_in[1];
    const float* bias = (const float*)d_in[2];
    const int*   src  = (const int*)d_in[3];
    const int*   dst  = (const int*)d_in[4];
    float* out = (float*)d_out;

    if (ws_size < WS_NEED) return;  // insufficient scratch -> loud failure

    char* w = (char*)d_ws;
    int* outd = (int*)w;
    int* ind  = outd + NA;
    int* rowp = outd + 2 * NA;
    int* bsum = outd + 3 * NA;                       // 256 ints
    float* normsrc = (float*)(outd + 3 * NA + 512);  // NN floats (< NA-512)
    int* csr  = outd + CSR_IOFF;
    unsigned short* hs  = (unsigned short*)(w + HS_OFF);
    unsigned short* wtp = (unsigned short*)(w + WT_OFF);
    int* rank = (int*)(w + RANK_OFF);

    hipMemsetAsync(outd, 0, (size_t)2 * NA * sizeof(int), stream);  // outd+ind

    k_count_conv<<<2048, 256, 0, stream>>>(src, dst, h, outd, ind, rank, hs);
    k_scan1<<<SCAN_NB, 1024, 0, stream>>>(ind, rowp, bsum);
    k_scan2<<<1, 128, 0, stream>>>(bsum);
    k_scan3<<<SCAN_NB, 1024, 0, stream>>>(rowp, bsum, outd, normsrc);
    k_scatter<<<2048, 256, 0, stream>>>(src, dst, rank, rowp, W, csr, wtp);
    k_aggemm<<<NN / 16, 256, 0, stream>>>(hs, csr, rowp, ind, normsrc, wtp, bias, out);
}